// Round 1
// baseline (3263.430 us; speedup 1.0000x reference)
//
#include <hip/hip_runtime.h>
#include <cfloat>
#include <climits>

#define NEG 0.2f
#define GEPS 1e-5f
#define D 6
#define H 13   // 2*D+1
#define KOUT 16

__device__ __forceinline__ float lrelu(float x){ return x >= 0.f ? x : NEG*x; }

// pack xyz (n,3) -> float4 {x,y,z,|p|^2}
__global__ void pack_kernel(const float* __restrict__ xyz, float4* __restrict__ out, int n){
  int i = blockIdx.x*blockDim.x + threadIdx.x;
  if (i >= n) return;
  float x = xyz[3*i], y = xyz[3*i+1], z = xyz[3*i+2];
  float sq;
  {
#pragma clang fp contract(off)
    sq = (x*x + y*y) + z*z;
  }
  out[i] = make_float4(x,y,z,sq);
}

// atomtypes (n,6) -> 2-layer MLP -> out (n,6)
__global__ void tt_kernel(const float* __restrict__ at_in,
                          const float* __restrict__ w1, const float* __restrict__ b1,
                          const float* __restrict__ w2, const float* __restrict__ b2,
                          float* __restrict__ out, int n){
  int i = blockIdx.x*blockDim.x + threadIdx.x;
  if (i >= n) return;
  float x[D], h[D];
  #pragma unroll
  for (int j=0;j<D;j++) x[j] = at_in[i*D+j];
  #pragma unroll
  for (int o=0;o<D;o++){
    float acc = b1[o];
    #pragma unroll
    for (int j=0;j<D;j++) acc += w1[o*D+j]*x[j];
    h[o] = lrelu(acc);
  }
  #pragma unroll
  for (int o=0;o<D;o++){
    float acc = b2[o];
    #pragma unroll
    for (int j=0;j<D;j++) acc += w2[o*D+j]*h[j];
    out[i*D+o] = acc;
  }
}

// Brute-force KNN. TPQ threads cooperate per query; each keeps a register
// top-KSEL (lexicographic (d2, idx), matching lax.top_k stability), merged in
// LDS by one lane. If DROP_MIN, the lexicographic minimum (the self point) is
// dropped, leaving KOUT=16 outputs.
template<int KSEL, bool DROP_MIN, int TPQ>
__global__ __launch_bounds__(256)
void knn_kernel(const float4* __restrict__ cand, int ncand,
                const float4* __restrict__ qp_arr, int nq,
                int* __restrict__ oidx, float* __restrict__ odist){
  constexpr int QPB = 256 / TPQ;
  __shared__ float sd[QPB*TPQ*KSEL];
  __shared__ int   si[QPB*TPQ*KSEL];
  const int g = threadIdx.x / TPQ, l = threadIdx.x % TPQ;
  const int q = blockIdx.x*QPB + g;
  float4 qp = make_float4(0.f,0.f,0.f,0.f);
  if (q < nq) qp = qp_arr[q];

  float bd[KSEL]; int bi[KSEL];
  #pragma unroll
  for (int t=0;t<KSEL;t++){ bd[t]=FLT_MAX; bi[t]=INT_MAX; }
  float cmd = FLT_MAX; int cmi = INT_MAX;

  if (q < nq){
    for (int j=l; j<ncand; j+=TPQ){
      float4 cp = cand[j];
      float d2;
      {
#pragma clang fp contract(off)
        float dot = qp.x*cp.x + qp.y*cp.y + qp.z*cp.z;
        d2 = (qp.w + cp.w) - 2.0f*dot;
      }
      if (d2 < cmd || (d2 == cmd && j < cmi)){
        bool done=false;
        #pragma unroll
        for (int t=0;t<KSEL;t++){
          if (!done && bd[t]==cmd && bi[t]==cmi){ bd[t]=d2; bi[t]=j; done=true; }
        }
        cmd=-FLT_MAX; cmi=-1;
        #pragma unroll
        for (int t=0;t<KSEL;t++){
          if (bd[t] > cmd || (bd[t]==cmd && bi[t]>cmi)){ cmd=bd[t]; cmi=bi[t]; }
        }
      }
    }
  }

  const int base = (g*TPQ + l)*KSEL;
  #pragma unroll
  for (int t=0;t<KSEL;t++){ sd[base+t]=bd[t]; si[base+t]=bi[t]; }
  __syncthreads();

  if (l==0 && q<nq){
    float md[KSEL]; int mi[KSEL];
    #pragma unroll
    for (int t=0;t<KSEL;t++){ md[t]=FLT_MAX; mi[t]=INT_MAX; }
    float mmd=FLT_MAX; int mmi=INT_MAX;
    const int mbase = g*TPQ*KSEL;
    for (int e=0;e<TPQ*KSEL;e++){
      float d2 = sd[mbase+e]; int j = si[mbase+e];
      if (d2 < mmd || (d2==mmd && j<mmi)){
        bool done=false;
        #pragma unroll
        for (int t=0;t<KSEL;t++){
          if (!done && md[t]==mmd && mi[t]==mmi){ md[t]=d2; mi[t]=j; done=true; }
        }
        mmd=-FLT_MAX; mmi=-1;
        #pragma unroll
        for (int t=0;t<KSEL;t++){
          if (md[t] > mmd || (md[t]==mmd && mi[t]>mmi)){ mmd=md[t]; mmi=mi[t]; }
        }
      }
    }
    int dropt = -1;
    if (DROP_MIN){
      float mnd=FLT_MAX; int mni=INT_MAX;
      #pragma unroll
      for (int t=0;t<KSEL;t++){
        if (md[t] < mnd || (md[t]==mnd && mi[t]<mni)){ mnd=md[t]; mni=mi[t]; dropt=t; }
      }
    }
    int w = 0;
    #pragma unroll
    for (int t=0;t<KSEL;t++){
      if (t==dropt) continue;
      int j = mi[t];
      float4 cp = cand[j];
      float dist;
      {
#pragma clang fp contract(off)
        float dx=qp.x-cp.x, dy=qp.y-cp.y, dz=qp.z-cp.z;
        dist = (dx*dx + dy*dy) + dz*dz;
      }
      oidx[q*KOUT + w] = j;
      odist[q*KOUT + w] = dist;
      w++;
    }
  }
}

// One message-passing block: out = self + lrelu(groupnorm(sum_k MLP(feat_k)))
template<bool SELF_ONES>
__global__ __launch_bounds__(256)
void mp_kernel(const float* __restrict__ self_feat,
               const float* __restrict__ nb_src,
               const int* __restrict__ idx,
               const float* __restrict__ dists,
               const float* __restrict__ w1g, const float* __restrict__ b1g,
               const float* __restrict__ w2g, const float* __restrict__ b2g,
               const float* __restrict__ gam, const float* __restrict__ bet,
               float* __restrict__ out, int n){
  __shared__ float w1[H*H], b1[H], w2[D*H], b2[D], gm[D], bt[D];
  for (int t=threadIdx.x; t<H*H; t+=blockDim.x) w1[t]=w1g[t];
  if (threadIdx.x < H) b1[threadIdx.x]=b1g[threadIdx.x];
  for (int t=threadIdx.x; t<D*H; t+=blockDim.x) w2[t]=w2g[t];
  if (threadIdx.x < D){
    b2[threadIdx.x]=b2g[threadIdx.x];
    gm[threadIdx.x]=gam[threadIdx.x];
    bt[threadIdx.x]=bet[threadIdx.x];
  }
  __syncthreads();
  int p = blockIdx.x*blockDim.x + threadIdx.x;
  if (p >= n) return;

  float s[D];
  #pragma unroll
  for (int j=0;j<D;j++) s[j] = SELF_ONES ? 1.0f : self_feat[p*D+j];
  float msg[D] = {0,0,0,0,0,0};

  for (int t=0;t<KOUT;t++){
    int j = idx[p*KOUT+t];
    float dd = dists[p*KOUT+t];
    float f[H];
    #pragma unroll
    for (int c=0;c<D;c++) f[c]=s[c];
    #pragma unroll
    for (int c=0;c<D;c++) f[D+c]=nb_src[j*D+c];
    f[2*D]=dd;
    float h[H];
    #pragma unroll
    for (int o=0;o<H;o++){
      float acc=b1[o];
      #pragma unroll
      for (int c=0;c<H;c++) acc += w1[o*H+c]*f[c];
      h[o]=lrelu(acc);
    }
    #pragma unroll
    for (int o=0;o<D;o++){
      float acc=b2[o];
      #pragma unroll
      for (int c=0;c<H;c++) acc += w2[o*H+c]*h[c];
      msg[o]+=acc;
    }
  }

  // group norm (2 groups of 3 channels) + lrelu + residual
  float y[D];
  #pragma unroll
  for (int gi=0; gi<2; gi++){
    float m0=msg[gi*3+0], m1=msg[gi*3+1], m2=msg[gi*3+2];
    float mu = ((m0+m1)+m2) / 3.0f;
    float d0=m0-mu, d1=m1-mu, d2v=m2-mu;
    float var = ((d0*d0 + d1*d1) + d2v*d2v) / 3.0f;
    float inv = 1.0f / sqrtf(var + GEPS);
    y[gi*3+0] = d0*inv;
    y[gi*3+1] = d1*inv;
    y[gi*3+2] = d2v*inv;
  }
  #pragma unroll
  for (int c=0;c<D;c++){
    float v = y[c]*gm[c] + bt[c];
    out[p*D+c] = s[c] + lrelu(v);
  }
}

extern "C" void kernel_launch(void* const* d_in, const int* in_sizes, int n_in,
                              void* d_out, int out_size, void* d_ws, size_t ws_size,
                              hipStream_t stream){
  const float* xyz       = (const float*)d_in[0];
  const float* atom_xyz  = (const float*)d_in[1];
  const float* atomtypes = (const float*)d_in[2];
  const float* tt_w1 = (const float*)d_in[5];
  const float* tt_b1 = (const float*)d_in[6];
  const float* tt_w2 = (const float*)d_in[7];
  const float* tt_b2 = (const float*)d_in[8];
  const float* aa_w1 = (const float*)d_in[9];
  const float* aa_b1 = (const float*)d_in[10];
  const float* aa_w2 = (const float*)d_in[11];
  const float* aa_b2 = (const float*)d_in[12];
  const float* aa_gamma = (const float*)d_in[13];
  const float* aa_beta  = (const float*)d_in[14];
  const float* em_w1 = (const float*)d_in[15];
  const float* em_b1 = (const float*)d_in[16];
  const float* em_w2 = (const float*)d_in[17];
  const float* em_b2 = (const float*)d_in[18];
  const float* em_gamma = (const float*)d_in[19];
  const float* em_beta  = (const float*)d_in[20];

  const int n_pts = in_sizes[0]/3;
  const int n_at  = in_sizes[1]/3;

  char* ws = (char*)d_ws;
  float4* atomsP = (float4*)ws; ws += (size_t)n_at*sizeof(float4);
  float4* ptsP   = (float4*)ws; ws += (size_t)n_pts*sizeof(float4);
  float* fa   = (float*)ws; ws += (size_t)n_at*D*4;
  float* fb   = (float*)ws; ws += (size_t)n_at*D*4;
  int*   idxA = (int*)ws;   ws += (size_t)n_at*KOUT*4;
  float* distA= (float*)ws; ws += (size_t)n_at*KOUT*4;
  int*   idxP = (int*)ws;   ws += (size_t)n_pts*KOUT*4;
  float* distP= (float*)ws; ws += (size_t)n_pts*KOUT*4;
  float* ea   = (float*)ws; ws += (size_t)n_pts*D*4;
  float* eb   = (float*)ws; ws += (size_t)n_pts*D*4;
  float* outf = (float*)d_out;

  pack_kernel<<<(n_at +255)/256,256,0,stream>>>(atom_xyz, atomsP, n_at);
  pack_kernel<<<(n_pts+255)/256,256,0,stream>>>(xyz, ptsP, n_pts);

  tt_kernel<<<(n_at+255)/256,256,0,stream>>>(atomtypes, tt_w1,tt_b1,tt_w2,tt_b2, fa, n_at);

  knn_kernel<17,true,8><<<(n_at+31)/32,256,0,stream>>>(atomsP, n_at, atomsP, n_at, idxA, distA);

  mp_kernel<false><<<(n_at+255)/256,256,0,stream>>>(fa, fa, idxA, distA,
      aa_w1+0*H*H, aa_b1+0*H, aa_w2+0*D*H, aa_b2+0*D, aa_gamma+0*D, aa_beta+0*D, fb, n_at);
  mp_kernel<false><<<(n_at+255)/256,256,0,stream>>>(fb, fb, idxA, distA,
      aa_w1+1*H*H, aa_b1+1*H, aa_w2+1*D*H, aa_b2+1*D, aa_gamma+1*D, aa_beta+1*D, fa, n_at);
  mp_kernel<false><<<(n_at+255)/256,256,0,stream>>>(fa, fa, idxA, distA,
      aa_w1+2*H*H, aa_b1+2*H, aa_w2+2*D*H, aa_b2+2*D, aa_gamma+2*D, aa_beta+2*D, fb, n_at);
  // final atom features in fb

  knn_kernel<16,false,8><<<(n_pts+31)/32,256,0,stream>>>(atomsP, n_at, ptsP, n_pts, idxP, distP);

  mp_kernel<true ><<<(n_pts+255)/256,256,0,stream>>>(nullptr, fb, idxP, distP,
      em_w1+0*H*H, em_b1+0*H, em_w2+0*D*H, em_b2+0*D, em_gamma+0*D, em_beta+0*D, ea, n_pts);
  mp_kernel<false><<<(n_pts+255)/256,256,0,stream>>>(ea, fb, idxP, distP,
      em_w1+1*H*H, em_b1+1*H, em_w2+1*D*H, em_b2+1*D, em_gamma+1*D, em_beta+1*D, eb, n_pts);
  mp_kernel<false><<<(n_pts+255)/256,256,0,stream>>>(eb, fb, idxP, distP,
      em_w1+2*H*H, em_b1+2*H, em_w2+2*D*H, em_b2+2*D, em_gamma+2*D, em_beta+2*D, outf, n_pts);
}

// Round 2
// 328.940 us; speedup vs baseline: 9.9211x; 9.9211x over previous
//
#include <hip/hip_runtime.h>
#include <cfloat>
#include <climits>

#define NEG 0.2f
#define GEPS 1e-5f
#define D 6
#define H 13   // 2*D+1
#define KOUT 16

__device__ __forceinline__ float lrelu(float x){ return x >= 0.f ? x : NEG*x; }

// pack xyz (n,3) -> float4 {x,y,z,|p|^2}
__global__ void pack_kernel(const float* __restrict__ xyz, float4* __restrict__ out, int n){
  int i = blockIdx.x*blockDim.x + threadIdx.x;
  if (i >= n) return;
  float x = xyz[3*i], y = xyz[3*i+1], z = xyz[3*i+2];
  float sq;
  {
#pragma clang fp contract(off)
    sq = (x*x + y*y) + z*z;
  }
  out[i] = make_float4(x,y,z,sq);
}

// atomtypes (n,6) -> 2-layer MLP -> out (n,6)
__global__ void tt_kernel(const float* __restrict__ at_in,
                          const float* __restrict__ w1, const float* __restrict__ b1,
                          const float* __restrict__ w2, const float* __restrict__ b2,
                          float* __restrict__ out, int n){
  int i = blockIdx.x*blockDim.x + threadIdx.x;
  if (i >= n) return;
  float x[D], h[D];
  #pragma unroll
  for (int j=0;j<D;j++) x[j] = at_in[i*D+j];
  #pragma unroll
  for (int o=0;o<D;o++){
    float acc = b1[o];
    #pragma unroll
    for (int j=0;j<D;j++) acc += w1[o*D+j]*x[j];
    h[o] = lrelu(acc);
  }
  #pragma unroll
  for (int o=0;o<D;o++){
    float acc = b2[o];
    #pragma unroll
    for (int j=0;j<D;j++) acc += w2[o*D+j]*h[j];
    out[i*D+o] = acc;
  }
}

// ascending lexicographic (d, i) bitonic sort across 64 lanes
__device__ __forceinline__ void sort64(float& d, int& i, int lane){
  #pragma unroll
  for (int k = 2; k <= 64; k <<= 1){
    #pragma unroll
    for (int j = k >> 1; j >= 1; j >>= 1){
      float od = __shfl_xor(d, j);
      int   oi = __shfl_xor(i, j);
      bool lower = (lane & j) == 0;
      bool asc   = (lane & k) == 0;
      bool oless = (od < d) || (od == d && oi < i);
      bool take  = (lower == asc) ? oless : !oless;
      d = take ? od : d;
      i = take ? oi : i;
    }
  }
}

// Wave-per-query exact KNN.
// Pass 1: per-lane lex-min over its candidate slice.
// Sort the 64 lane-minima; (T,Ti) = KSEL-th smallest is an upper bound on the
// true KSEL-th neighbor (>=KSEL distinct candidates are <=lex it).
// Pass 2: ballot-compact all candidates <=lex (T,Ti) into LDS (expected ~20).
// Phase 3: bitonic-sort the buffer, emit KOUT entries starting at OUT_OFF
// (OUT_OFF=1 drops the self point for the atom-atom KNN).
template<int KSEL, int OUT_OFF>
__global__ __launch_bounds__(256)
void knn_kernel(const float4* __restrict__ cand, int ncand,
                const float4* __restrict__ qp_arr, int nq,
                int* __restrict__ oidx, float* __restrict__ odist){
  constexpr int CAP = 128;
  __shared__ float sbd[4][CAP];
  __shared__ int   sbi[4][CAP];
  const int wid  = threadIdx.x >> 6;
  const int lane = threadIdx.x & 63;
  const int q = blockIdx.x*4 + wid;
  if (q >= nq) return;                 // wave-uniform; no __syncthreads below
  const float4 qp = qp_arr[q];

  // ---- pass 1: per-lane lexicographic min ----
  float m = FLT_MAX; int mi = INT_MAX;
  for (int j = lane; j < ncand; j += 64){
    float4 cp = cand[j];
    float d2;
    {
#pragma clang fp contract(off)
      float dot = qp.x*cp.x + qp.y*cp.y + qp.z*cp.z;
      d2 = (qp.w + cp.w) - 2.0f*dot;
    }
    bool lt = (d2 < m) || (d2 == m && j < mi);
    m  = lt ? d2 : m;
    mi = lt ? j  : mi;
  }
  sort64(m, mi, lane);
  const float T  = __shfl(m,  KSEL-1);
  const int   Ti = __shfl(mi, KSEL-1);

  // ---- pass 2: collect all candidates <=lex (T,Ti) ----
  int cnt = 0;
  for (int j = lane; j < ncand; j += 64){
    float4 cp = cand[j];
    float d2;
    {
#pragma clang fp contract(off)
      float dot = qp.x*cp.x + qp.y*cp.y + qp.z*cp.z;
      d2 = (qp.w + cp.w) - 2.0f*dot;
    }
    bool acc = (d2 < T) || (d2 == T && j <= Ti);
    unsigned long long msk = __ballot(acc);
    if (acc){
      int ofs = cnt + __popcll(msk & ((1ULL << lane) - 1ULL));
      if (ofs < CAP){ sbd[wid][ofs] = d2; sbi[wid][ofs] = j; }
    }
    cnt += __popcll(msk);
  }
  const int C = __shfl(cnt, 0);        // lane 0 runs the most iterations
  __threadfence_block();               // drain ds_writes before cross-lane reads

  if (C <= 64){
    float d = (lane < C) ? sbd[wid][lane] : FLT_MAX;
    int   i = (lane < C) ? sbi[wid][lane] : INT_MAX;
    sort64(d, i, lane);
    if (lane >= OUT_OFF && lane < OUT_OFF + KOUT){
      int t = lane - OUT_OFF;
      float4 cp = cand[i];
      float dist;
      {
#pragma clang fp contract(off)
        float dx = qp.x-cp.x, dy = qp.y-cp.y, dz = qp.z-cp.z;
        dist = (dx*dx + dy*dy) + dz*dz;
      }
      oidx[q*KOUT + t]  = i;
      odist[q*KOUT + t] = dist;
    }
  } else {
    // astronomically rare (needs <KSEL distinct lanes hit in first 64 draws)
    if (lane == 0){
      int Cc = C < CAP ? C : CAP;
      for (int t = 0; t < KSEL; t++){
        float bm = FLT_MAX; int bj = INT_MAX; int bp = -1;
        for (int e = 0; e < Cc; e++){
          float dv = sbd[wid][e]; int jv = sbi[wid][e];
          if (dv < bm || (dv == bm && jv < bj)){ bm = dv; bj = jv; bp = e; }
        }
        sbd[wid][bp] = FLT_MAX; sbi[wid][bp] = INT_MAX;
        if (t >= OUT_OFF){
          float4 cp = cand[bj];
          float dist;
          {
#pragma clang fp contract(off)
            float dx = qp.x-cp.x, dy = qp.y-cp.y, dz = qp.z-cp.z;
            dist = (dx*dx + dy*dy) + dz*dz;
          }
          oidx[q*KOUT + (t-OUT_OFF)]  = bj;
          odist[q*KOUT + (t-OUT_OFF)] = dist;
        }
      }
    }
  }
}

// One message-passing block: out = self + lrelu(groupnorm(sum_k MLP(feat_k)))
// 4 threads per point: each handles 4 of the 16 neighbors, shfl-reduce.
template<bool SELF_ONES>
__global__ __launch_bounds__(256)
void mp_kernel(const float* __restrict__ self_feat,
               const float* __restrict__ nb_src,
               const int* __restrict__ idx,
               const float* __restrict__ dists,
               const float* __restrict__ w1g, const float* __restrict__ b1g,
               const float* __restrict__ w2g, const float* __restrict__ b2g,
               const float* __restrict__ gam, const float* __restrict__ bet,
               float* __restrict__ out, int n){
  __shared__ float w1[H*H], b1v[H], w2[D*H], b2v[D], gm[D], bt[D];
  for (int t=threadIdx.x; t<H*H; t+=blockDim.x) w1[t]=w1g[t];
  if (threadIdx.x < H) b1v[threadIdx.x]=b1g[threadIdx.x];
  for (int t=threadIdx.x; t<D*H; t+=blockDim.x) w2[t]=w2g[t];
  if (threadIdx.x < D){
    b2v[threadIdx.x]=b2g[threadIdx.x];
    gm[threadIdx.x]=gam[threadIdx.x];
    bt[threadIdx.x]=bet[threadIdx.x];
  }
  __syncthreads();
  int tt = blockIdx.x*blockDim.x + threadIdx.x;
  int p = tt >> 2, sub = tt & 3;
  if (p >= n) return;                  // whole 4-group exits together

  float s[D];
  #pragma unroll
  for (int j=0;j<D;j++) s[j] = SELF_ONES ? 1.0f : self_feat[p*D+j];
  float msg[D] = {0,0,0,0,0,0};

  #pragma unroll
  for (int u=0;u<KOUT/4;u++){
    int k = u*4 + sub;
    int j = idx[p*KOUT+k];
    float dd = dists[p*KOUT+k];
    float f[H];
    #pragma unroll
    for (int c=0;c<D;c++) f[c]=s[c];
    #pragma unroll
    for (int c=0;c<D;c++) f[D+c]=nb_src[j*D+c];
    f[2*D]=dd;
    float h[H];
    #pragma unroll
    for (int o=0;o<H;o++){
      float acc=b1v[o];
      #pragma unroll
      for (int c=0;c<H;c++) acc += w1[o*H+c]*f[c];
      h[o]=lrelu(acc);
    }
    #pragma unroll
    for (int o=0;o<D;o++){
      float acc=b2v[o];
      #pragma unroll
      for (int c=0;c<H;c++) acc += w2[o*H+c]*h[c];
      msg[o]+=acc;
    }
  }

  // reduce the 4 partial msg vectors within the 4-lane group
  #pragma unroll
  for (int c=0;c<D;c++){
    msg[c] += __shfl_xor(msg[c], 1);
    msg[c] += __shfl_xor(msg[c], 2);
  }

  if (sub == 0){
    float y[D];
    #pragma unroll
    for (int gi=0; gi<2; gi++){
      float m0=msg[gi*3+0], m1=msg[gi*3+1], m2=msg[gi*3+2];
      float mu = ((m0+m1)+m2) / 3.0f;
      float d0=m0-mu, d1=m1-mu, d2v=m2-mu;
      float var = ((d0*d0 + d1*d1) + d2v*d2v) / 3.0f;
      float inv = 1.0f / sqrtf(var + GEPS);
      y[gi*3+0] = d0*inv;
      y[gi*3+1] = d1*inv;
      y[gi*3+2] = d2v*inv;
    }
    #pragma unroll
    for (int c=0;c<D;c++){
      float v = y[c]*gm[c] + bt[c];
      out[p*D+c] = s[c] + lrelu(v);
    }
  }
}

extern "C" void kernel_launch(void* const* d_in, const int* in_sizes, int n_in,
                              void* d_out, int out_size, void* d_ws, size_t ws_size,
                              hipStream_t stream){
  const float* xyz       = (const float*)d_in[0];
  const float* atom_xyz  = (const float*)d_in[1];
  const float* atomtypes = (const float*)d_in[2];
  const float* tt_w1 = (const float*)d_in[5];
  const float* tt_b1 = (const float*)d_in[6];
  const float* tt_w2 = (const float*)d_in[7];
  const float* tt_b2 = (const float*)d_in[8];
  const float* aa_w1 = (const float*)d_in[9];
  const float* aa_b1 = (const float*)d_in[10];
  const float* aa_w2 = (const float*)d_in[11];
  const float* aa_b2 = (const float*)d_in[12];
  const float* aa_gamma = (const float*)d_in[13];
  const float* aa_beta  = (const float*)d_in[14];
  const float* em_w1 = (const float*)d_in[15];
  const float* em_b1 = (const float*)d_in[16];
  const float* em_w2 = (const float*)d_in[17];
  const float* em_b2 = (const float*)d_in[18];
  const float* em_gamma = (const float*)d_in[19];
  const float* em_beta  = (const float*)d_in[20];

  const int n_pts = in_sizes[0]/3;
  const int n_at  = in_sizes[1]/3;

  char* ws = (char*)d_ws;
  float4* atomsP = (float4*)ws; ws += (size_t)n_at*sizeof(float4);
  float4* ptsP   = (float4*)ws; ws += (size_t)n_pts*sizeof(float4);
  float* fa   = (float*)ws; ws += (size_t)n_at*D*4;
  float* fb   = (float*)ws; ws += (size_t)n_at*D*4;
  int*   idxA = (int*)ws;   ws += (size_t)n_at*KOUT*4;
  float* distA= (float*)ws; ws += (size_t)n_at*KOUT*4;
  int*   idxP = (int*)ws;   ws += (size_t)n_pts*KOUT*4;
  float* distP= (float*)ws; ws += (size_t)n_pts*KOUT*4;
  float* outf = (float*)d_out;
  float* ea   = (float*)ws; ws += (size_t)n_pts*D*4;
  float* eb   = (float*)ws; ws += (size_t)n_pts*D*4;

  pack_kernel<<<(n_at +255)/256,256,0,stream>>>(atom_xyz, atomsP, n_at);
  pack_kernel<<<(n_pts+255)/256,256,0,stream>>>(xyz, ptsP, n_pts);

  tt_kernel<<<(n_at+255)/256,256,0,stream>>>(atomtypes, tt_w1,tt_b1,tt_w2,tt_b2, fa, n_at);

  knn_kernel<17,1><<<(n_at+3)/4,256,0,stream>>>(atomsP, n_at, atomsP, n_at, idxA, distA);

  mp_kernel<false><<<(n_at*4+255)/256,256,0,stream>>>(fa, fa, idxA, distA,
      aa_w1+0*H*H, aa_b1+0*H, aa_w2+0*D*H, aa_b2+0*D, aa_gamma+0*D, aa_beta+0*D, fb, n_at);
  mp_kernel<false><<<(n_at*4+255)/256,256,0,stream>>>(fb, fb, idxA, distA,
      aa_w1+1*H*H, aa_b1+1*H, aa_w2+1*D*H, aa_b2+1*D, aa_gamma+1*D, aa_beta+1*D, fa, n_at);
  mp_kernel<false><<<(n_at*4+255)/256,256,0,stream>>>(fa, fa, idxA, distA,
      aa_w1+2*H*H, aa_b1+2*H, aa_w2+2*D*H, aa_b2+2*D, aa_gamma+2*D, aa_beta+2*D, fb, n_at);
  // final atom features in fb

  knn_kernel<16,0><<<(n_pts+3)/4,256,0,stream>>>(atomsP, n_at, ptsP, n_pts, idxP, distP);

  mp_kernel<true ><<<(n_pts*4+255)/256,256,0,stream>>>(nullptr, fb, idxP, distP,
      em_w1+0*H*H, em_b1+0*H, em_w2+0*D*H, em_b2+0*D, em_gamma+0*D, em_beta+0*D, ea, n_pts);
  mp_kernel<false><<<(n_pts*4+255)/256,256,0,stream>>>(ea, fb, idxP, distP,
      em_w1+1*H*H, em_b1+1*H, em_w2+1*D*H, em_b2+1*D, em_gamma+1*D, em_beta+1*D, eb, n_pts);
  mp_kernel<false><<<(n_pts*4+255)/256,256,0,stream>>>(eb, fb, idxP, distP,
      em_w1+2*H*H, em_b1+2*H, em_w2+2*D*H, em_b2+2*D, em_gamma+2*D, em_beta+2*D, outf, n_pts);
}